// Round 1
// 296.936 us; speedup vs baseline: 1.0065x; 1.0065x over previous
//
#include <hip/hip_runtime.h>
#include <hip/hip_bf16.h>

typedef __attribute__((ext_vector_type(8))) short short8;
typedef __attribute__((ext_vector_type(4))) float floatx4;

__device__ __forceinline__ float sigm(float x) { return 1.0f / (1.0f + __expf(-x)); }

__device__ __forceinline__ unsigned short f2bf(float v) {
  union { __hip_bfloat16 h; unsigned short u; } cv;
  cv.h = __float2bfloat16(v);
  return cv.u;
}

__device__ __forceinline__ void glds16(const void* g, void* l) {
  __builtin_amdgcn_global_load_lds((const __attribute__((address_space(1))) void*)g,
                                   (__attribute__((address_space(3))) void*)l, 16, 0, 0);
}

// ---------------- prep: fold ia/im/bias into padded bf16 weights ----------------
// Combined channel c (0..170): c<18 -> det row c (scaled by im, bias im*(b + W.ia));
//                              c>=18 -> kpt row c-18 (bias bk). Rows 171..191 zero.
struct PrepArgs {
  const float *w, *b, *im, *ia, *wk, *bk;
  unsigned short* Wp;
  float* bias;
  int C;
};

__global__ void prep_kernel(PrepArgs A0, PrepArgs A1, PrepArgs A2) {
  PrepArgs A = (blockIdx.y == 0) ? A0 : (blockIdx.y == 1) ? A1 : A2;
  const int n = blockIdx.x;   // 0..191
  const int t = threadIdx.x;  // 0..63
  const int C = A.C;
  unsigned short* wrow = A.Wp + (size_t)n * C;
  if (n >= 171) {
    for (int k = t; k < C; k += 64) wrow[k] = 0;
    if (t == 0) A.bias[n] = 0.0f;
    return;
  }
  if (n < 18) {
    const float* src = A.w + (size_t)n * C;
    const float sc = A.im[n];
    float dot = 0.0f;
    for (int k = t; k < C; k += 64) {
      float v = src[k];
      dot += v * A.ia[k];
      wrow[k] = f2bf(v * sc);
    }
#pragma unroll
    for (int off = 32; off > 0; off >>= 1) dot += __shfl_down(dot, off);
    if (t == 0) A.bias[n] = sc * (A.b[n] + dot);
  } else {
    const float* src = A.wk + (size_t)(n - 18) * C;
    for (int k = t; k < C; k += 64) wrow[k] = f2bf(src[k]);
    if (t == 0) A.bias[n] = A.bk[n - 18];
  }
}

// ---------------- fully pipelined fused GEMM (bf16 MFMA) + decode ----------------
// Block = 64 m x 176 n, 4 waves (wave = 16m x 176n). BK = 64.
// A: direct global->fragment-register gathers (no LDS), double-buffered in regs,
//    prefetched one full iteration ahead.
// B: global_load_lds 16B, XOR-chunk-swizzled LDS [192][128B], DOUBLE-BUFFERED:
//    glds for tile it+1 issued during iteration it, so the loop-top
//    s_waitcnt vmcnt(16) drains loads issued a whole iteration earlier.
// One s_barrier per K-step (was 2). 3 blocks/CU (LDS 2x24576).
#define LDS_BYTES 49152  // B dbuf 2*[192][128B]=49152; epilogue 32*180*4=23040 reuses

template <int SC, int C, int HW, int W>
__device__ __forceinline__ void gemm_decode(const float* __restrict__ feat,
                                            const unsigned short* __restrict__ Wp,
                                            const float* __restrict__ bias,
                                            float* __restrict__ out, int tile, char* smem) {
  constexpr float STRD = (SC == 0) ? 8.0f : (SC == 1) ? 16.0f : 32.0f;
  constexpr int ZOFF = (SC == 0) ? 0 : (SC == 1) ? 19200 : 24000;
  constexpr int I = C / 64;

  const int t = threadIdx.x;
  const int lane = t & 63;
  const int wv = t >> 6;
  const int l15 = lane & 15;
  const int quad = lane >> 4;

  char* BB = smem;             // 2 x [192][128B] bf16, XOR-chunk swizzled
  float* Elds = (float*)smem;  // epilogue [32][180] fp32 (reuse)

  // ---- A: direct-to-fragment gather mapping ----
  // fragment layout (16x16x32): lane holds A[row=l15][k=quad*8+j] (af0), +32 (af1)
  const int mA = tile * 64 + wv * 16 + l15;
  const int bA = mA / HW;
  const int pA = mA - bA * HW;
  const float* fbase = feat + ((size_t)bA * C + quad * 8) * (size_t)HW + pA;

  // ---- B glds per-lane source mapping (8 rows per instr, chunk XOR row&7) ----
  const int rsub = lane >> 3;         // row within 8-row group
  const int csw = (lane & 7) ^ rsub;  // swizzled 16B-chunk index
  const char* WpB = (const char*)Wp;

  floatx4 acc[11];
#pragma unroll
  for (int nj = 0; nj < 11; ++nj) acc[nj] = (floatx4){0.f, 0.f, 0.f, 0.f};

  // B fragment read offsets (buffer base added at use)
  const int c0 = quad ^ (l15 & 7);
  const int bOff0 = l15 * 128 + c0 * 16;
  const int bOff1 = l15 * 128 + (c0 ^ 4) * 16;

  float v[16];
  auto loadA = [&](int it) {
    const float* g = fbase + (size_t)it * 64 * HW;
#pragma unroll
    for (int j = 0; j < 8; ++j) {
      v[j] = g[(size_t)j * HW];
      v[j + 8] = g[(size_t)(32 + j) * HW];
    }
  };
  auto stageB = [&](int it, int buf) {
#pragma unroll
    for (int j = 0; j < 6; ++j) {
      const int rowb = wv * 48 + j * 8;
      const void* gsrc = WpB + ((size_t)(rowb + rsub) * C + (size_t)it * 64) * 2 + csw * 16;
      glds16(gsrc, BB + buf * 24576 + rowb * 128);
    }
  };

  // prologue: issue B(0) then A(0); steady-state in-flight = 6 glds (older) + 16 A
  stageB(0, 0);
  loadA(0);

  for (int it = 0; it < I; ++it) {
    // Drain only the 6 glds for buf[it&1] (issued one iteration ago; latency hidden).
    // Barrier closes both hazards: (a) all waves' B(it) landed, (b) all waves are
    // done reading buf[(it+1)&1] (their it-1 MFMAs consumed the ds_reads).
    asm volatile("s_waitcnt vmcnt(16)\n\ts_barrier" ::: "memory");
    // prefetch next B tile into the other buffer (stays in flight across this iter)
    stageB((it + 1 < I) ? it + 1 : 0, (it + 1) & 1);
    __builtin_amdgcn_sched_barrier(0);  // pin: glds issued before A cvt's vmcnt wait
    // convert A(it) -> bf16 fragments (compiler inserts vmcnt(6): waits only A loads)
    short8 af0, af1;
#pragma unroll
    for (int j = 0; j < 8; ++j) {
      af0[j] = (short)f2bf(v[j]);
      af1[j] = (short)f2bf(v[j + 8]);
    }
    __builtin_amdgcn_sched_barrier(0);
    // prefetch next A tile (16 loads stay in flight across the next loop-top wait)
    loadA((it + 1 < I) ? it + 1 : it);
    __builtin_amdgcn_sched_barrier(0);
    // MFMA: wave computes 16m x 176n from buf[it&1]
    const char* bBase = BB + (it & 1) * 24576;
#pragma unroll
    for (int nj = 0; nj < 11; ++nj) {
      short8 b0 = *(const short8*)(bBase + bOff0 + (size_t)nj * 2048);
      short8 b1 = *(const short8*)(bBase + bOff1 + (size_t)nj * 2048);
      acc[nj] = __builtin_amdgcn_mfma_f32_16x16x32_bf16(af0, b0, acc[nj], 0, 0, 0);
      acc[nj] = __builtin_amdgcn_mfma_f32_16x16x32_bf16(af1, b1, acc[nj], 0, 0, 0);
    }
  }

  // ---------------- epilogue: 2 chunks of 32 rows ----------------
  float bj[11];
#pragma unroll
  for (int nj = 0; nj < 11; ++nj) bj[nj] = bias[nj * 16 + l15];

#pragma unroll
  for (int c = 0; c < 2; ++c) {
    __syncthreads();  // full drain (incl. dummy prefetches); staging LDS dead -> Elds
    if ((wv >> 1) == c) {
      const int rbase = (wv & 1) * 16 + quad * 4;
#pragma unroll
      for (int nj = 0; nj < 11; ++nj)
#pragma unroll
        for (int r = 0; r < 4; ++r)
          Elds[(rbase + r) * 180 + nj * 16 + l15] = acc[nj][r] + bj[nj];
    }
    __syncthreads();
    if (t < 192) {
      const int task = t >> 1, half = t & 1;
      const int row = task & 31, a = task >> 5;
      const int m = tile * 64 + c * 32 + row;
      const int bb = m / HW;
      const int p = m - bb * HW;
      const float fx = (float)(p % W);
      const float fy = (float)(p / W);
      float* L = Elds + row * 180 + a * 57;
      if (half == 0) {
        float aw, ah;
        if constexpr (SC == 0) {
          aw = (a == 0) ? 19.f : (a == 1) ? 44.f : 38.f;
          ah = (a == 0) ? 27.f : (a == 1) ? 40.f : 94.f;
        } else if constexpr (SC == 1) {
          aw = (a == 0) ? 96.f : (a == 1) ? 86.f : 180.f;
          ah = (a == 0) ? 68.f : (a == 1) ? 152.f : 137.f;
        } else {
          aw = (a == 0) ? 140.f : (a == 1) ? 303.f : 238.f;
          ah = (a == 0) ? 301.f : (a == 1) ? 264.f : 542.f;
        }
        float r0 = L[0], r1 = L[1], r2 = L[2], r3 = L[3], r4 = L[4], r5 = L[5];
        L[0] = (sigm(r0) * 2.f - 0.5f + fx) * STRD;
        L[1] = (sigm(r1) * 2.f - 0.5f + fy) * STRD;
        float tw = sigm(r2) * 2.f;
        L[2] = tw * tw * aw;
        float th = sigm(r3) * 2.f;
        L[3] = th * th * ah;
        L[4] = sigm(r4);
        L[5] = sigm(r5);
#pragma unroll
        for (int kp = 0; kp < 8; ++kp) {
          float kx = L[6 + 3 * kp], ky = L[7 + 3 * kp], kc = L[8 + 3 * kp];
          L[6 + 3 * kp] = (kx * 2.f - 0.5f + fx) * STRD;
          L[7 + 3 * kp] = (ky * 2.f - 0.5f + fy) * STRD;
          L[8 + 3 * kp] = sigm(kc);
        }
      } else {
#pragma unroll
        for (int kp = 8; kp < 17; ++kp) {
          float kx = L[6 + 3 * kp], ky = L[7 + 3 * kp], kc = L[8 + 3 * kp];
          L[6 + 3 * kp] = (kx * 2.f - 0.5f + fx) * STRD;
          L[7 + 3 * kp] = (ky * 2.f - 0.5f + fy) * STRD;
          L[8 + 3 * kp] = sigm(kc);
        }
      }
    }
    __syncthreads();
    for (int i = t; i < 96 * 57; i += 256) {
      int sr = i / 57;
      int j = i - sr * 57;
      int a = sr >> 5, row = sr & 31;
      int m = tile * 64 + c * 32 + row;
      int bb = m / HW;
      int p = m - bb * HW;
      out[((size_t)bb * 25200 + (size_t)(ZOFF + a * HW + p)) * 57 + j] =
          Elds[row * 180 + a * 57 + j];
    }
  }
}

__global__ __launch_bounds__(256, 3) void main_kernel(
    const float* __restrict__ f0, const float* __restrict__ f1, const float* __restrict__ f2,
    const unsigned short* __restrict__ Wp0, const unsigned short* __restrict__ Wp1,
    const unsigned short* __restrict__ Wp2, const float* __restrict__ b0,
    const float* __restrict__ b1, const float* __restrict__ b2, float* __restrict__ out) {
  __shared__ __align__(16) char smem[LDS_BYTES];
  const int bid = blockIdx.x;
  // longest blocks (scale 2, C=1024) first to amortize the tail
  if (bid < 100)
    gemm_decode<2, 1024, 400, 20>(f2, Wp2, b2, out, bid, smem);
  else if (bid < 500)
    gemm_decode<1, 512, 1600, 40>(f1, Wp1, b1, out, bid - 100, smem);
  else
    gemm_decode<0, 256, 6400, 80>(f0, Wp0, b0, out, bid - 500, smem);
}

extern "C" void kernel_launch(void* const* d_in, const int* in_sizes, int n_in, void* d_out,
                              int out_size, void* d_ws, size_t ws_size, hipStream_t stream) {
  const float *f[3], *ia[3], *w[3], *b[3], *im[3], *wk[3], *bk[3];
  for (int s = 0; s < 3; ++s) {
    f[s] = (const float*)d_in[7 * s + 0];
    ia[s] = (const float*)d_in[7 * s + 1];
    w[s] = (const float*)d_in[7 * s + 2];
    b[s] = (const float*)d_in[7 * s + 3];
    im[s] = (const float*)d_in[7 * s + 4];
    wk[s] = (const float*)d_in[7 * s + 5];
    bk[s] = (const float*)d_in[7 * s + 6];
  }
  // workspace: Wp[s] has 192 rows (rows 176..191 zero, for uniform glds coverage)
  // Wp0 98304B | Wp1 196608B | Wp2 393216B | 3x bias 192 f32
  char* ws = (char*)d_ws;
  unsigned short* Wp0 = (unsigned short*)(ws + 0);
  unsigned short* Wp1 = (unsigned short*)(ws + 98304);
  unsigned short* Wp2 = (unsigned short*)(ws + 294912);
  float* bias0 = (float*)(ws + 688128);
  float* bias1 = (float*)(ws + 688896);
  float* bias2 = (float*)(ws + 689664);

  PrepArgs A0 = {w[0], b[0], im[0], ia[0], wk[0], bk[0], Wp0, bias0, 256};
  PrepArgs A1 = {w[1], b[1], im[1], ia[1], wk[1], bk[1], Wp1, bias1, 512};
  PrepArgs A2 = {w[2], b[2], im[2], ia[2], wk[2], bk[2], Wp2, bias2, 1024};
  prep_kernel<<<dim3(192, 3), 64, 0, stream>>>(A0, A1, A2);

  main_kernel<<<2100, 256, 0, stream>>>(f[0], f[1], f[2], Wp0, Wp1, Wp2, bias0, bias1, bias2,
                                        (float*)d_out);
}